// Round 2
// baseline (366.454 us; speedup 1.0000x reference)
//
#include <hip/hip_runtime.h>

// GIN: 3 layers of {agg = scatter_sum(h[src] -> dst); h = relu(((1+eps)h + agg) @ W + b)}
// then per-graph segment-sum readout (graph_ids sorted) -> 2-layer MLP.
//
// R15: R14's depth-2 pipeline never engaged: VGPR_Count=32 proves the
//      scheduler sank issue_rows loads to their uses (launch_bounds(128,8)
//      capped regs at 64; sinking minimizes liveness). Fix:
//      (a) __builtin_amdgcn_sched_barrier(0) between each issue phase and
//          the following consume -> loads MUST be emitted early; compiler's
//          counted vmcnt keeps them in flight across the consume;
//      (b) launch_bounds(128,6): VGPR cap ~84 so the 2 RowBufs + 3 idx
//          vectors live in registers (predict VGPR ~72-84, no spill).
// R14: depth-2 pipeline shape + 128-thread blocks. R13: uniform-trip gather
//      (all 4 lane-groups split ONE node's edges, trip = deg/4 uniform).
// R12: merged pre. R10: fused layer + atomic-free readout. R9: bucketed CSR.
// R7: f16 H. R5: MFMA bf16 hi/lo 3-product gemm.

#define SPLIT 16
#define NBLK 512     // edge chunks for bucket build
#define BS 512       // nodes per bucket (pow2)
#define PF 6         // prefetched row slots per node (fast path deg <= 24)

typedef unsigned short ushort_t;
typedef __bf16 v8bf __attribute__((ext_vector_type(8)));
typedef float v4f __attribute__((ext_vector_type(4)));

__device__ __forceinline__ float h2f_lo(unsigned int v) {
    return (float)__builtin_bit_cast(_Float16, (unsigned short)(v & 0xffffu));
}
__device__ __forceinline__ float h2f_hi(unsigned int v) {
    return (float)__builtin_bit_cast(_Float16, (unsigned short)(v >> 16));
}
__device__ __forceinline__ unsigned int f2h(float f) {
    return (unsigned int)__builtin_bit_cast(unsigned short, (_Float16)f);
}
__device__ __forceinline__ int rdl_shfl(int v, int srcLane) {
    return __builtin_amdgcn_readfirstlane(__shfl(v, srcLane, 64));
}

// Merged: bucket_count (blocks 0..NBLK-1) | cast (next castBlocks) | prep_w (rest)
__global__ __launch_bounds__(256) void pre_kernel(
        const int* __restrict__ dst, int* __restrict__ cnt2d,
        int E, int nbkt, int ebpb,
        const float* __restrict__ x, ushort_t* __restrict__ xh, int n4, int castBlocks,
        const float* __restrict__ W, ushort_t* __restrict__ whi,
        ushort_t* __restrict__ wlo, int wtotal) {
    __shared__ int lcnt[256];
    int t = threadIdx.x;
    int blk = blockIdx.x;
    if (blk < NBLK) {
        lcnt[t] = 0;
        __syncthreads();
        int base = blk * ebpb;
        int end = min(base + ebpb, E);
        for (int i = base + t; i < end; i += 256)
            atomicAdd(&lcnt[dst[i] >> 9], 1);
        __syncthreads();
        if (t < nbkt) cnt2d[(size_t)blk * nbkt + t] = lcnt[t];
    } else if (blk < NBLK + castBlocks) {
        int i = (blk - NBLK) * 256 + t;
        if (i < n4) {
            float4 v = ((const float4*)x)[i];
            uint2 p;
            p.x = f2h(v.x) | (f2h(v.y) << 16);
            p.y = f2h(v.z) | (f2h(v.w) << 16);
            ((uint2*)xh)[i] = p;
        }
    } else {
        int i = (blk - NBLK - castBlocks) * 256 + t;
        if (i < wtotal) {
            int l = i >> 12, r = i & 4095;
            int n = r >> 6, k = r & 63;
            float w = W[l * 4096 + k * 64 + n];
            __bf16 h = (__bf16)w;
            float rem = w - (float)h;
            whi[i] = __builtin_bit_cast(ushort_t, h);
            wlo[i] = __builtin_bit_cast(ushort_t, (__bf16)rem);
        }
    }
}

// B1: block b scans column b of cnt2d over NBLK chunks -> blkoff[b][blk], btot[b]
__global__ __launch_bounds__(256) void colscan_kernel(
        const int* __restrict__ cnt2d, int* __restrict__ blkoff,
        int* __restrict__ btot, int nbkt) {
    __shared__ int sh[256];
    int b = blockIdx.x, t = threadIdx.x;
    int i0 = 2 * t, i1 = 2 * t + 1;
    int v0 = cnt2d[(size_t)i0 * nbkt + b];
    int v1 = cnt2d[(size_t)i1 * nbkt + b];
    int pair = v0 + v1;
    sh[t] = pair;
    __syncthreads();
    for (int off = 1; off < 256; off <<= 1) {
        int u = (t >= off) ? sh[t - off] : 0;
        __syncthreads();
        sh[t] += u;
        __syncthreads();
    }
    int ex = sh[t] - pair;
    blkoff[(size_t)b * NBLK + i0] = ex;
    blkoff[(size_t)b * NBLK + i1] = ex + v0;
    if (t == 255) btot[b] = sh[255];
}

// B2: scan btot[nbkt] -> bbase[nbkt+1]; offsets[N]=E.
__global__ __launch_bounds__(256) void bucket_base_kernel(
        const int* __restrict__ btot, int* __restrict__ bbase,
        int* __restrict__ offsets, int nbkt, int N, int E) {
    __shared__ int sh[256];
    int t = threadIdx.x;
    int v = (t < nbkt) ? btot[t] : 0;
    sh[t] = v;
    __syncthreads();
    for (int off = 1; off < 256; off <<= 1) {
        int u = (t >= off) ? sh[t - off] : 0;
        __syncthreads();
        sh[t] += u;
        __syncthreads();
    }
    if (t < nbkt) bbase[t] = sh[t] - v;
    if (t == 0) { bbase[nbkt] = E; offsets[N] = E; }
}

// C: scatter edges into bucket regions as packed (src<<9)|d_local.
__global__ __launch_bounds__(256) void bucket_scatter_kernel(
        const int* __restrict__ src, const int* __restrict__ dst,
        const int* __restrict__ bbase, const int* __restrict__ blkoff,
        unsigned int* __restrict__ bkt, int E, int nbkt, int ebpb) {
    __shared__ int lbase[256];
    __shared__ int lrank[256];
    int t = threadIdx.x;
    if (t < nbkt) lbase[t] = bbase[t] + blkoff[(size_t)t * NBLK + blockIdx.x];
    lrank[t] = 0;
    __syncthreads();
    int base = blockIdx.x * ebpb;
    int end = min(base + ebpb, E);
    for (int i = base + t; i < end; i += 256) {
        int d = dst[i];
        int b = d >> 9;
        int r = atomicAdd(&lrank[b], 1);
        bkt[lbase[b] + r] = ((unsigned int)src[i] << 9) | (unsigned int)(d & (BS - 1));
    }
}

// D: block b = bucket b. LDS hist + scan -> offsets + csr (LDS atomics only).
__global__ __launch_bounds__(256) void csr_build_kernel(
        const unsigned int* __restrict__ bkt, const int* __restrict__ bbase,
        int* __restrict__ offsets, int* __restrict__ csr, int N, int nbkt) {
    __shared__ int cnt[BS];
    __shared__ int rank[BS];
    __shared__ int sh[256];
    int b = blockIdx.x, t = threadIdx.x;
    cnt[t] = 0; cnt[t + 256] = 0;
    rank[t] = 0; rank[t + 256] = 0;
    __syncthreads();
    int base = bbase[b], end = bbase[b + 1];
    for (int i = base + t; i < end; i += 256)
        atomicAdd(&cnt[bkt[i] & (BS - 1)], 1);
    __syncthreads();
    int i0 = 2 * t, i1 = 2 * t + 1;
    int v0 = cnt[i0], v1 = cnt[i1];
    int pair = v0 + v1;
    sh[t] = pair;
    __syncthreads();
    for (int off = 1; off < 256; off <<= 1) {
        int u = (t >= off) ? sh[t - off] : 0;
        __syncthreads();
        sh[t] += u;
        __syncthreads();
    }
    int ex = sh[t] - pair;
    __syncthreads();
    cnt[i0] = ex;
    cnt[i1] = ex + v0;
    __syncthreads();
    int d0 = (b << 9) + i0;
    if (d0 <= N) offsets[d0] = base + cnt[i0];
    int d1 = (b << 9) + i1;
    if (d1 <= N) offsets[d1] = base + cnt[i1];
    for (int i = base + t; i < end; i += 256) {
        unsigned int v = bkt[i];
        int dl = v & (BS - 1);
        int r = atomicAdd(&rank[dl], 1);
        csr[base + cnt[dl] + r] = (int)(v >> 9);
    }
}

// Register row-buffer for one node's gather: PF uint2 slots + self row.
struct RowBuf {
    uint2 r0, r1, r2, r3, r4, r5;
    uint2 sf;
};

// Issue phase: masked loads of up to PF row-slots for this node + self row.
// trip/dg are wave-uniform (SGPR via readfirstlane at call site).
__device__ __forceinline__ void issue_rows(RowBuf& b, const ushort_t* __restrict__ hin,
        int idxv, int dg, int node, int N, int g, int sl) {
    int trip = min((dg + 3) >> 2, PF);
#define ISSUE_SLOT(nn, rr)                                         \
    if (nn < trip) {                                               \
        int p = g + 4 * nn;                                        \
        int s = __shfl(idxv, p, 64);                               \
        uint2 v = make_uint2(0u, 0u);                              \
        if (p < dg) v = ((const uint2*)hin)[s * 16 + sl];          \
        b.rr = v;                                                  \
    }
    ISSUE_SLOT(0, r0) ISSUE_SLOT(1, r1) ISSUE_SLOT(2, r2)
    ISSUE_SLOT(3, r3) ISSUE_SLOT(4, r4) ISSUE_SLOT(5, r5)
#undef ISSUE_SLOT
    b.sf = make_uint2(0u, 0u);
    if (node < N) b.sf = ((const uint2*)hin)[node * 16 + sl];
}

// Consume phase: accumulate buffered rows, rare deg>4*PF fallback, reduce,
// self term, store row into wave-private LDS.
__device__ __forceinline__ void consume_node(const RowBuf& b, const ushort_t* __restrict__ hin,
        const int* __restrict__ csr, int idxv, int e0, int dg,
        int g, int sl, float eps1, float* myrows, int k) {
    int trip = min((dg + 3) >> 2, PF);
    float ax = 0.f, ay = 0.f, az = 0.f, aw = 0.f;
#define ACC(vv) { ax += h2f_lo(vv.x); ay += h2f_hi(vv.x);          \
                  az += h2f_lo(vv.y); aw += h2f_hi(vv.y); }
    if (0 < trip) ACC(b.r0)
    if (1 < trip) ACC(b.r1)
    if (2 < trip) ACC(b.r2)
    if (3 < trip) ACC(b.r3)
    if (4 < trip) ACC(b.r4)
    if (5 < trip) ACC(b.r5)
    if (dg > 4 * PF) {                      // rare tail (Poisson-12, ~0.1%)
        int dcap = min(dg, 64);
        for (int j = 4 * PF + g; j < dcap; j += 4) {
            int s = __shfl(idxv, j, 64);
            uint2 v = ((const uint2*)hin)[s * 16 + sl];
            ACC(v)
        }
        for (int j = 64 + g; j < dg; j += 4) {   // astronomically rare
            int s = csr[e0 + j];
            uint2 v = ((const uint2*)hin)[s * 16 + sl];
            ACC(v)
        }
    }
#undef ACC
    ax += __shfl_xor(ax, 16, 64); ax += __shfl_xor(ax, 32, 64);
    ay += __shfl_xor(ay, 16, 64); ay += __shfl_xor(ay, 32, 64);
    az += __shfl_xor(az, 16, 64); az += __shfl_xor(az, 32, 64);
    aw += __shfl_xor(aw, 16, 64); aw += __shfl_xor(aw, 32, 64);
    // self term: sf pre-zeroed for OOB nodes, so unconditional fma is safe
    ax = fmaf(eps1, h2f_lo(b.sf.x), ax);
    ay = fmaf(eps1, h2f_hi(b.sf.x), ay);
    az = fmaf(eps1, h2f_lo(b.sf.y), az);
    aw = fmaf(eps1, h2f_hi(b.sf.y), aw);
    if (g == 0) {
        float4 r4; r4.x = ax; r4.y = ay; r4.z = az; r4.w = aw;
        *(float4*)&myrows[k * 64 + sl * 4] = r4;
    }
}

// Fused GIN layer, R15: wave = 16-node tile, depth-2 pipelined gather with
// sched_barrier(0) fences so the issue loads CANNOT sink into the consume.
// While node k is consumed out of registers, node k+1's rows + self and the
// CSR index vectors for k+2/k+3 are already in flight (counted vmcnt).
__global__ __launch_bounds__(128, 6) void layer_kernel(
        const ushort_t* __restrict__ hin, ushort_t* __restrict__ hout,
        const int* __restrict__ offsets, const int* __restrict__ csr,
        const ushort_t* __restrict__ wt_hi, const ushort_t* __restrict__ wt_lo,
        const float* __restrict__ gin_b, const float* __restrict__ eps_arr,
        int layer, int N) {
    __shared__ float rows[2 * 16 * 64];   // 8KB: 2 waves x 16 nodes x 64 f32
    int t = threadIdx.x;
    int wv = t >> 6, lane = t & 63;
    int tile = blockIdx.x * 2 + wv;
    if (tile * 16 >= N) return;           // waves independent
    float* myrows = rows + wv * 16 * 64;
    float eps1 = 1.0f + eps_arr[layer];

    int g  = lane >> 4;    // edge group 0..3
    int sl = lane & 15;    // uint2 slot (dims 4sl..4sl+3)

    // one coalesced load covers all 17 offsets for this tile
    int off_l = offsets[min(tile * 16 + lane, N)];

#define EDEG(kk, e0v, dgv) { e0v = rdl_shfl(off_l, kk); \
                             dgv = rdl_shfl(off_l, (kk) + 1) - e0v; }

    // pipeline prologue: idx for nodes 0,1,2 then rows+self for node 0
    int e0P, dgP, e0Q, dgQ, e0R, dgR;
    EDEG(0, e0P, dgP); EDEG(1, e0Q, dgQ); EDEG(2, e0R, dgR);
    int idxP = (lane < dgP) ? csr[e0P + lane] : 0;
    int idxQ = (lane < dgQ) ? csr[e0Q + lane] : 0;
    int idxR = (lane < dgR) ? csr[e0R + lane] : 0;
    RowBuf bufA, bufB;
    issue_rows(bufA, hin, idxP, dgP, tile * 16, N, g, sl);

    for (int kk = 0; kk < 8; ++kk) {
        int k = kk << 1;
        // issue idx(k+3)
        int e0S = 0, dgS = 0, idxS = 0;
        if (k + 3 < 16) { EDEG(k + 3, e0S, dgS); idxS = (lane < dgS) ? csr[e0S + lane] : 0; }
        // issue rows(k+1); fence so these loads cannot sink past consume(k)
        issue_rows(bufB, hin, idxQ, dgQ, tile * 16 + k + 1, N, g, sl);
        __builtin_amdgcn_sched_barrier(0);
        consume_node(bufA, hin, csr, idxP, e0P, dgP, g, sl, eps1, myrows, k);
        // issue idx(k+4)
        int e0T = 0, dgT = 0, idxT = 0;
        if (k + 4 < 16) { EDEG(k + 4, e0T, dgT); idxT = (lane < dgT) ? csr[e0T + lane] : 0; }
        // issue rows(k+2); fence again, then consume node k+1
        if (k + 2 < 16) issue_rows(bufA, hin, idxR, dgR, tile * 16 + k + 2, N, g, sl);
        __builtin_amdgcn_sched_barrier(0);
        consume_node(bufB, hin, csr, idxQ, e0Q, dgQ, g, sl, eps1, myrows, k + 1);
        // rotate pipeline state
        idxP = idxR; e0P = e0R; dgP = dgR;
        idxQ = idxS; e0Q = e0S; dgQ = dgS;
        idxR = idxT; e0R = e0T; dgR = dgT;
    }
#undef EDEG
    // intra-wave LDS ordering: compiler emits lgkmcnt before reads; no barrier.

    int c = lane & 15;     // node within tile / n-index
    int q = lane >> 4;     // quad
    int node16 = tile * 16 + c;

    const ushort_t* Whi = wt_hi + layer * 4096;
    const ushort_t* Wlo = wt_lo + layer * 4096;
    const float*    bl  = gin_b + layer * 64;

    v8bf bhi[2], blo2[2];
    #pragma unroll
    for (int kt = 0; kt < 2; ++kt) {
        float4 f0 = *(float4*)&myrows[c * 64 + kt * 32 + q * 8];
        float4 f1 = *(float4*)&myrows[c * 64 + kt * 32 + q * 8 + 4];
        float xs[8] = {f0.x, f0.y, f0.z, f0.w, f1.x, f1.y, f1.z, f1.w};
        #pragma unroll
        for (int j = 0; j < 8; ++j) {
            __bf16 h = (__bf16)xs[j];
            bhi[kt][j] = h;
            blo2[kt][j] = (__bf16)(xs[j] - (float)h);
        }
    }

    #pragma unroll
    for (int mt = 0; mt < 4; ++mt) {
        v4f acc = {0.f, 0.f, 0.f, 0.f};
        #pragma unroll
        for (int kt = 0; kt < 2; ++kt) {
            int dim = mt * 16 + c;
            size_t off = (size_t)dim * 64 + kt * 32 + q * 8;
            v8bf ah = __builtin_bit_cast(v8bf, *(const uint4*)(Whi + off));
            v8bf al = __builtin_bit_cast(v8bf, *(const uint4*)(Wlo + off));
            acc = __builtin_amdgcn_mfma_f32_16x16x32_bf16(ah, bhi[kt],  acc, 0, 0, 0);
            acc = __builtin_amdgcn_mfma_f32_16x16x32_bf16(ah, blo2[kt], acc, 0, 0, 0);
            acc = __builtin_amdgcn_mfma_f32_16x16x32_bf16(al, bhi[kt],  acc, 0, 0, 0);
        }
        float4 bv = ((const float4*)(bl + mt * 16))[q];
        float o0 = fmaxf(acc[0] + bv.x, 0.f);
        float o1 = fmaxf(acc[1] + bv.y, 0.f);
        float o2 = fmaxf(acc[2] + bv.z, 0.f);
        float o3 = fmaxf(acc[3] + bv.w, 0.f);
        uint2 pk;
        pk.x = f2h(o0) | (f2h(o1) << 16);
        pk.y = f2h(o2) | (f2h(o3) << 16);
        if (node16 < N)
            *(uint2*)(hout + (size_t)node16 * 64 + mt * 16 + q * 4) = pk;
    }
}

// Phase 1: dense partials, no atomics. gpart[(graph*SPLIT+sp)*192 + t].
__global__ __launch_bounds__(192) void readout_part_kernel(
        const ushort_t* __restrict__ H, const int* __restrict__ gids,
        float* __restrict__ gpart, int N) {
    int graph = blockIdx.x / SPLIT;
    int sp    = blockIdx.x % SPLIT;
    int lo = 0, hi = N;
    while (lo < hi) { int mid = (lo + hi) >> 1; if (gids[mid] < graph) lo = mid + 1; else hi = mid; }
    int start = lo;
    int lo2 = start, hi2 = N;
    while (lo2 < hi2) { int mid = (lo2 + hi2) >> 1; if (gids[mid] < graph + 1) lo2 = mid + 1; else hi2 = mid; }
    int end = lo2;
    int t = threadIdx.x;            // 0..191
    int l = t >> 6, d = t & 63;
    float acc = 0.0f;
    int cnt = end - start;
    if (cnt > 0) {
        int per = (cnt + SPLIT - 1) / SPLIT;
        int cs = start + sp * per;
        int ce = min(cs + per, end);
        const ushort_t* Hl = H + (size_t)l * N * 64;
        for (int n = cs; n < ce; ++n)
            acc += (float)__builtin_bit_cast(_Float16, Hl[(size_t)n * 64 + d]);
    }
    gpart[(size_t)(graph * SPLIT + sp) * 192 + t] = acc;   // unconditional
}

// Phase 2 fused with MLP: sum 16 partials -> gr, then 2-layer MLP.
__global__ __launch_bounds__(192) void mlp_kernel(
        const float* __restrict__ gpart,
        const float* __restrict__ W1, const float* __restrict__ b1,
        const float* __restrict__ W2, const float* __restrict__ b2,
        float* __restrict__ out) {
    __shared__ float gr[192];
    __shared__ float hid[128];
    int graph = blockIdx.x;
    int t = threadIdx.x;
    float a = 0.f;
    #pragma unroll
    for (int sp = 0; sp < SPLIT; ++sp)
        a += gpart[(size_t)(graph * SPLIT + sp) * 192 + t];
    gr[t] = a;
    __syncthreads();
    if (t < 128) {
        float s = b1[t];
        for (int k = 0; k < 192; ++k) s = fmaf(gr[k], W1[k * 128 + t], s);
        hid[t] = fmaxf(s, 0.0f);
    }
    __syncthreads();
    if (t < 32) {
        float s = b2[t];
        for (int k = 0; k < 128; ++k) s = fmaf(hid[k], W2[k * 32 + t], s);
        out[graph * 32 + t] = s;
    }
}

extern "C" void kernel_launch(void* const* d_in, const int* in_sizes, int n_in,
                              void* d_out, int out_size, void* d_ws, size_t ws_size,
                              hipStream_t stream) {
    const float* x     = (const float*)d_in[0];
    const float* gin_W = (const float*)d_in[1];
    const float* gin_b = (const float*)d_in[2];
    const float* eps   = (const float*)d_in[3];
    const float* r_W1  = (const float*)d_in[4];
    const float* r_b1  = (const float*)d_in[5];
    const float* r_W2  = (const float*)d_in[6];
    const float* r_b2  = (const float*)d_in[7];
    const int*   src   = (const int*)d_in[8];
    const int*   dst   = (const int*)d_in[9];
    const int*   gids  = (const int*)d_in[10];

    int N = in_sizes[0] / 64;       // 100000
    int E = in_sizes[8];            // 1200000
    int B = out_size / 32;          // 256

    int nbkt = (N + BS - 1) / BS;   // 196 (<= 256)
    int ebpb = (E + NBLK - 1) / NBLK;
    int n4 = N * 64 / 4;
    int castBlocks = (n4 + 255) / 256;
    int wtotal = 3 * 4096;
    int prepBlocks = (wtotal + 255) / 256;

    // workspace layout (4B words), all regions fully written before read:
    //   gpart[B*SPLIT*192]
    //   cnt2d[NBLK*nbkt] | blkoff[nbkt*NBLK] | btot[nbkt] | bbase[nbkt+1]
    //   offsets[N+1] | bkt[E] | csr[E] | pad
    //   xh[N*64 f16] | H[3*N*64 f16] | whi[3*4096] | wlo[3*4096]
    int* ws       = (int*)d_ws;
    float* gpart  = (float*)ws;
    int* cnt2d    = ws + (size_t)B * SPLIT * 192;
    int* blkoff   = cnt2d + (size_t)NBLK * nbkt;
    int* btot     = blkoff + (size_t)nbkt * NBLK;
    int* bbase    = btot + nbkt;
    int* offsets  = bbase + (nbkt + 1);
    unsigned int* bkt = (unsigned int*)(offsets + (N + 1));
    int* csr      = (int*)(bkt + E);
    size_t w      = (size_t)(csr + E - ws);
    w = (w + 15) & ~(size_t)15;     // 64B align
    ushort_t* xh  = (ushort_t*)(ws + w);
    ushort_t* H   = xh + (size_t)N * 64;
    ushort_t* whi = H + 3 * (size_t)N * 64;
    ushort_t* wlo = whi + 3 * 4096;

    pre_kernel<<<NBLK + castBlocks + prepBlocks, 256, 0, stream>>>(
        dst, cnt2d, E, nbkt, ebpb, x, xh, n4, castBlocks, gin_W, whi, wlo, wtotal);
    colscan_kernel<<<nbkt, 256, 0, stream>>>(cnt2d, blkoff, btot, nbkt);
    bucket_base_kernel<<<1, 256, 0, stream>>>(btot, bbase, offsets, nbkt, N, E);
    bucket_scatter_kernel<<<NBLK, 256, 0, stream>>>(src, dst, bbase, blkoff, bkt, E, nbkt, ebpb);
    csr_build_kernel<<<nbkt, 256, 0, stream>>>(bkt, bbase, offsets, csr, N, nbkt);

    int lbk = (N + 31) / 32;        // 2 tiles (waves) of 16 nodes per block
    ushort_t* H0 = H;
    ushort_t* H1 = H + (size_t)N * 64;
    ushort_t* H2 = H + 2 * (size_t)N * 64;

    layer_kernel<<<lbk, 128, 0, stream>>>(xh, H0, offsets, csr, whi, wlo, gin_b, eps, 0, N);
    layer_kernel<<<lbk, 128, 0, stream>>>(H0, H1, offsets, csr, whi, wlo, gin_b, eps, 1, N);
    layer_kernel<<<lbk, 128, 0, stream>>>(H1, H2, offsets, csr, whi, wlo, gin_b, eps, 2, N);

    readout_part_kernel<<<B * SPLIT, 192, 0, stream>>>(H, gids, gpart, N);
    mlp_kernel<<<B, 192, 0, stream>>>(gpart, r_W1, r_b1, r_W2, r_b2, (float*)d_out);
}

// Round 5
// 307.332 us; speedup vs baseline: 1.1924x; 1.1924x over previous
//
#include <hip/hip_runtime.h>

// GIN: 3 layers of {agg = scatter_sum(h[src] -> dst); h = relu(((1+eps)h + agg) @ W + b)}
// then per-graph segment-sum readout (graph_ids sorted) -> 2-layer MLP.
//
// R18: flat-batch gather on the known-good R13 skeleton. R14/R15 (register
//      rotating pipeline) were unwound by the scheduler (VGPR 32/40 = loads
//      sunk to uses); R16 (global_load_lds staging) failed correctness;
//      R17 (raw asm loads) faulted. New shape, plain HIP, fail-to-neutral:
//      (a) all 16 idx loads issued upfront (unrolled, clamped, independent);
//      (b) 2 nodes per batch: 12 masked row-slot loads + 2 self rows all
//          textually before consumption (constant-indexed reg arrays), ONE
//          sched_barrier(0) pinning loads-before-consume per batch;
//      (c) compiler's incremental vmcnt leaves the 2nd node's loads in
//          flight while the 1st is consumed. Worst case = R13 serial order.
// R13: uniform-trip gather (4 lane-groups split ONE node's edges, trip =
//      deg/4 wave-uniform), wave-autonomous 16-node tile, MFMA epilogue.
// R12: merged pre. R10: fused layer + atomic-free readout. R9: bucketed CSR.
// R7: f16 H. R5: MFMA bf16 hi/lo 3-product gemm.

#define SPLIT 16
#define NBLK 512     // edge chunks for bucket build
#define BS 512       // nodes per bucket (pow2)

typedef unsigned short ushort_t;
typedef __bf16 v8bf __attribute__((ext_vector_type(8)));
typedef float v4f __attribute__((ext_vector_type(4)));

__device__ __forceinline__ float h2f_lo(unsigned int v) {
    return (float)__builtin_bit_cast(_Float16, (unsigned short)(v & 0xffffu));
}
__device__ __forceinline__ float h2f_hi(unsigned int v) {
    return (float)__builtin_bit_cast(_Float16, (unsigned short)(v >> 16));
}
__device__ __forceinline__ unsigned int f2h(float f) {
    return (unsigned int)__builtin_bit_cast(unsigned short, (_Float16)f);
}

// Merged: bucket_count (blocks 0..NBLK-1) | cast (next castBlocks) | prep_w (rest)
__global__ __launch_bounds__(256) void pre_kernel(
        const int* __restrict__ dst, int* __restrict__ cnt2d,
        int E, int nbkt, int ebpb,
        const float* __restrict__ x, ushort_t* __restrict__ xh, int n4, int castBlocks,
        const float* __restrict__ W, ushort_t* __restrict__ whi,
        ushort_t* __restrict__ wlo, int wtotal) {
    __shared__ int lcnt[256];
    int t = threadIdx.x;
    int blk = blockIdx.x;
    if (blk < NBLK) {
        lcnt[t] = 0;
        __syncthreads();
        int base = blk * ebpb;
        int end = min(base + ebpb, E);
        for (int i = base + t; i < end; i += 256)
            atomicAdd(&lcnt[dst[i] >> 9], 1);
        __syncthreads();
        if (t < nbkt) cnt2d[(size_t)blk * nbkt + t] = lcnt[t];
    } else if (blk < NBLK + castBlocks) {
        int i = (blk - NBLK) * 256 + t;
        if (i < n4) {
            float4 v = ((const float4*)x)[i];
            uint2 p;
            p.x = f2h(v.x) | (f2h(v.y) << 16);
            p.y = f2h(v.z) | (f2h(v.w) << 16);
            ((uint2*)xh)[i] = p;
        }
    } else {
        int i = (blk - NBLK - castBlocks) * 256 + t;
        if (i < wtotal) {
            int l = i >> 12, r = i & 4095;
            int n = r >> 6, k = r & 63;
            float w = W[l * 4096 + k * 64 + n];
            __bf16 h = (__bf16)w;
            float rem = w - (float)h;
            whi[i] = __builtin_bit_cast(ushort_t, h);
            wlo[i] = __builtin_bit_cast(ushort_t, (__bf16)rem);
        }
    }
}

// B1: block b scans column b of cnt2d over NBLK chunks -> blkoff[b][blk], btot[b]
__global__ __launch_bounds__(256) void colscan_kernel(
        const int* __restrict__ cnt2d, int* __restrict__ blkoff,
        int* __restrict__ btot, int nbkt) {
    __shared__ int sh[256];
    int b = blockIdx.x, t = threadIdx.x;
    int i0 = 2 * t, i1 = 2 * t + 1;
    int v0 = cnt2d[(size_t)i0 * nbkt + b];
    int v1 = cnt2d[(size_t)i1 * nbkt + b];
    int pair = v0 + v1;
    sh[t] = pair;
    __syncthreads();
    for (int off = 1; off < 256; off <<= 1) {
        int u = (t >= off) ? sh[t - off] : 0;
        __syncthreads();
        sh[t] += u;
        __syncthreads();
    }
    int ex = sh[t] - pair;
    blkoff[(size_t)b * NBLK + i0] = ex;
    blkoff[(size_t)b * NBLK + i1] = ex + v0;
    if (t == 255) btot[b] = sh[255];
}

// B2: scan btot[nbkt] -> bbase[nbkt+1]; offsets[N]=E.
__global__ __launch_bounds__(256) void bucket_base_kernel(
        const int* __restrict__ btot, int* __restrict__ bbase,
        int* __restrict__ offsets, int nbkt, int N, int E) {
    __shared__ int sh[256];
    int t = threadIdx.x;
    int v = (t < nbkt) ? btot[t] : 0;
    sh[t] = v;
    __syncthreads();
    for (int off = 1; off < 256; off <<= 1) {
        int u = (t >= off) ? sh[t - off] : 0;
        __syncthreads();
        sh[t] += u;
        __syncthreads();
    }
    if (t < nbkt) bbase[t] = sh[t] - v;
    if (t == 0) { bbase[nbkt] = E; offsets[N] = E; }
}

// C: scatter edges into bucket regions as packed (src<<9)|d_local.
__global__ __launch_bounds__(256) void bucket_scatter_kernel(
        const int* __restrict__ src, const int* __restrict__ dst,
        const int* __restrict__ bbase, const int* __restrict__ blkoff,
        unsigned int* __restrict__ bkt, int E, int nbkt, int ebpb) {
    __shared__ int lbase[256];
    __shared__ int lrank[256];
    int t = threadIdx.x;
    if (t < nbkt) lbase[t] = bbase[t] + blkoff[(size_t)t * NBLK + blockIdx.x];
    lrank[t] = 0;
    __syncthreads();
    int base = blockIdx.x * ebpb;
    int end = min(base + ebpb, E);
    for (int i = base + t; i < end; i += 256) {
        int d = dst[i];
        int b = d >> 9;
        int r = atomicAdd(&lrank[b], 1);
        bkt[lbase[b] + r] = ((unsigned int)src[i] << 9) | (unsigned int)(d & (BS - 1));
    }
}

// D: block b = bucket b. LDS hist + scan -> offsets + csr (LDS atomics only).
__global__ __launch_bounds__(256) void csr_build_kernel(
        const unsigned int* __restrict__ bkt, const int* __restrict__ bbase,
        int* __restrict__ offsets, int* __restrict__ csr, int N, int nbkt) {
    __shared__ int cnt[BS];
    __shared__ int rank[BS];
    __shared__ int sh[256];
    int b = blockIdx.x, t = threadIdx.x;
    cnt[t] = 0; cnt[t + 256] = 0;
    rank[t] = 0; rank[t + 256] = 0;
    __syncthreads();
    int base = bbase[b], end = bbase[b + 1];
    for (int i = base + t; i < end; i += 256)
        atomicAdd(&cnt[bkt[i] & (BS - 1)], 1);
    __syncthreads();
    int i0 = 2 * t, i1 = 2 * t + 1;
    int v0 = cnt[i0], v1 = cnt[i1];
    int pair = v0 + v1;
    sh[t] = pair;
    __syncthreads();
    for (int off = 1; off < 256; off <<= 1) {
        int u = (t >= off) ? sh[t - off] : 0;
        __syncthreads();
        sh[t] += u;
        __syncthreads();
    }
    int ex = sh[t] - pair;
    __syncthreads();
    cnt[i0] = ex;
    cnt[i1] = ex + v0;
    __syncthreads();
    int d0 = (b << 9) + i0;
    if (d0 <= N) offsets[d0] = base + cnt[i0];
    int d1 = (b << 9) + i1;
    if (d1 <= N) offsets[d1] = base + cnt[i1];
    for (int i = base + t; i < end; i += 256) {
        unsigned int v = bkt[i];
        int dl = v & (BS - 1);
        int r = atomicAdd(&rank[dl], 1);
        csr[base + cnt[dl] + r] = (int)(v >> 9);
    }
}

// consume one node from a 6-slot register buffer (+tail fallback), reduce,
// self term, store row into wave-private LDS. kk must be a compile-time
// constant (unrolled caller) so idxa[kk]/buf[j] stay register-resident.
#define CONSUME_NODE(kk, dgv, e0v, buf, sf) { \
    float ax = 0.f, ay = 0.f, az = 0.f, aw = 0.f; \
    _Pragma("unroll") \
    for (int j = 0; j < 6; ++j) { \
        if (g + 4 * j < (dgv)) { \
            ax += h2f_lo(buf[j].x); ay += h2f_hi(buf[j].x); \
            az += h2f_lo(buf[j].y); aw += h2f_hi(buf[j].y); } } \
    if ((dgv) > 24) {                   /* rare tail (Poisson-12, ~0.1%) */ \
        int dc_ = min((dgv), 64); \
        for (int j = 24 + g; j < dc_; j += 4) { \
            int s_ = __shfl(idxa[kk], j, 64); \
            uint2 v_ = hp2[(size_t)s_ * 16 + sl]; \
            ax += h2f_lo(v_.x); ay += h2f_hi(v_.x); \
            az += h2f_lo(v_.y); aw += h2f_hi(v_.y); } \
        for (int j = 64 + g; j < (dgv); j += 4) {   /* astronomically rare */ \
            int s_ = csr[(e0v) + j]; \
            uint2 v_ = hp2[(size_t)s_ * 16 + sl]; \
            ax += h2f_lo(v_.x); ay += h2f_hi(v_.x); \
            az += h2f_lo(v_.y); aw += h2f_hi(v_.y); } } \
    ax += __shfl_xor(ax, 16, 64); ax += __shfl_xor(ax, 32, 64); \
    ay += __shfl_xor(ay, 16, 64); ay += __shfl_xor(ay, 32, 64); \
    az += __shfl_xor(az, 16, 64); az += __shfl_xor(az, 32, 64); \
    aw += __shfl_xor(aw, 16, 64); aw += __shfl_xor(aw, 32, 64); \
    if (tile * 16 + (kk) < N) { \
        ax = fmaf(eps1, h2f_lo(sf.x), ax); ay = fmaf(eps1, h2f_hi(sf.x), ay); \
        az = fmaf(eps1, h2f_lo(sf.y), az); aw = fmaf(eps1, h2f_hi(sf.y), aw); } \
    if (g == 0) { \
        float4 r4_; r4_.x = ax; r4_.y = ay; r4_.z = az; r4_.w = aw; \
        *(float4*)&myrows[(kk) * 64 + sl * 4] = r4_; } }

// Fused GIN layer, R18: wave = 16-node tile (autonomous, no barrier).
// Gather: 16 idx loads upfront; 8 flat batches of 2 nodes (12 row slots +
// 2 self rows issued before any consume, one sched_barrier per batch).
// Epilogue = R10 MFMA (unchanged from R13).
__global__ __launch_bounds__(256, 4) void layer_kernel(
        const ushort_t* __restrict__ hin, ushort_t* __restrict__ hout,
        const int* __restrict__ offsets, const int* __restrict__ csr,
        const ushort_t* __restrict__ wt_hi, const ushort_t* __restrict__ wt_lo,
        const float* __restrict__ gin_b, const float* __restrict__ eps_arr,
        int layer, int N, int E) {
    __shared__ float rows[4 * 16 * 64];   // 16KB: 4 waves x 16 nodes x 64 f32
    int t = threadIdx.x;
    int wv = t >> 6, lane = t & 63;
    int tile = blockIdx.x * 4 + wv;
    if (tile * 16 >= N) return;           // waves independent
    float* myrows = rows + wv * 16 * 64;
    const uint2* hp2 = (const uint2*)hin;
    float eps1 = 1.0f + eps_arr[layer];

    int g  = lane >> 4;    // edge group 0..3
    int sl = lane & 15;    // uint2 slot (dims 4sl..4sl+3)

    // one coalesced load covers all 17 offsets for this tile
    int off_l = offsets[min(tile * 16 + lane, N)];
    int e0a[17];
    #pragma unroll
    for (int k = 0; k < 17; ++k)
        e0a[k] = __builtin_amdgcn_readlane(off_l, k);

    // all 16 idx loads issued upfront: independent, clamped (deterministic),
    // masked at the select (which the compiler may sink -- loads stay early).
    int idxa[16];
    #pragma unroll
    for (int k = 0; k < 16; ++k) {
        int dg_ = e0a[k + 1] - e0a[k];
        int v_ = csr[min(e0a[k] + lane, E - 1)];
        idxa[k] = (lane < dg_) ? v_ : 0;
    }

    // 8 batches x 2 nodes: all 14 loads textually before any consumption.
    #pragma unroll
    for (int kb = 0; kb < 8; ++kb) {
        const int k = kb * 2;
        int e0A = e0a[k],     dgA = e0a[k + 1] - e0a[k];
        int e0B = e0a[k + 1], dgB = e0a[k + 2] - e0a[k + 1];
        uint2 b[6], c[6];
        #pragma unroll
        for (int j = 0; j < 6; ++j) {
            int p = g + 4 * j;
            int s = (p < dgA) ? __shfl(idxa[k], p, 64) : 0;
            b[j] = hp2[(size_t)s * 16 + sl];          // masked -> row 0 (L1)
        }
        #pragma unroll
        for (int j = 0; j < 6; ++j) {
            int p = g + 4 * j;
            int s = (p < dgB) ? __shfl(idxa[k + 1], p, 64) : 0;
            c[j] = hp2[(size_t)s * 16 + sl];
        }
        uint2 sfA = hp2[(size_t)min(tile * 16 + k,     N - 1) * 16 + sl];
        uint2 sfB = hp2[(size_t)min(tile * 16 + k + 1, N - 1) * 16 + sl];
        __builtin_amdgcn_sched_barrier(0);   // pin: loads above, consume below
        CONSUME_NODE(k,     dgA, e0A, b, sfA)
        CONSUME_NODE(k + 1, dgB, e0B, c, sfB)
    }
    // intra-wave LDS ordering: compiler emits lgkmcnt before reads; no barrier.

    int c2 = lane & 15;    // node within tile / n-index
    int q  = lane >> 4;    // quad
    int node16 = tile * 16 + c2;

    const ushort_t* Whi = wt_hi + layer * 4096;
    const ushort_t* Wlo = wt_lo + layer * 4096;
    const float*    bl  = gin_b + layer * 64;

    v8bf bhi[2], blo2[2];
    #pragma unroll
    for (int kt = 0; kt < 2; ++kt) {
        float4 f0 = *(float4*)&myrows[c2 * 64 + kt * 32 + q * 8];
        float4 f1 = *(float4*)&myrows[c2 * 64 + kt * 32 + q * 8 + 4];
        float xs[8] = {f0.x, f0.y, f0.z, f0.w, f1.x, f1.y, f1.z, f1.w};
        #pragma unroll
        for (int j = 0; j < 8; ++j) {
            __bf16 h = (__bf16)xs[j];
            bhi[kt][j] = h;
            blo2[kt][j] = (__bf16)(xs[j] - (float)h);
        }
    }

    #pragma unroll
    for (int mt = 0; mt < 4; ++mt) {
        v4f acc = {0.f, 0.f, 0.f, 0.f};
        #pragma unroll
        for (int kt = 0; kt < 2; ++kt) {
            int dim = mt * 16 + c2;
            size_t off = (size_t)dim * 64 + kt * 32 + q * 8;
            v8bf ah = __builtin_bit_cast(v8bf, *(const uint4*)(Whi + off));
            v8bf al = __builtin_bit_cast(v8bf, *(const uint4*)(Wlo + off));
            acc = __builtin_amdgcn_mfma_f32_16x16x32_bf16(ah, bhi[kt],  acc, 0, 0, 0);
            acc = __builtin_amdgcn_mfma_f32_16x16x32_bf16(ah, blo2[kt], acc, 0, 0, 0);
            acc = __builtin_amdgcn_mfma_f32_16x16x32_bf16(al, bhi[kt],  acc, 0, 0, 0);
        }
        float4 bv = ((const float4*)(bl + mt * 16))[q];
        float o0 = fmaxf(acc[0] + bv.x, 0.f);
        float o1 = fmaxf(acc[1] + bv.y, 0.f);
        float o2 = fmaxf(acc[2] + bv.z, 0.f);
        float o3 = fmaxf(acc[3] + bv.w, 0.f);
        uint2 pk;
        pk.x = f2h(o0) | (f2h(o1) << 16);
        pk.y = f2h(o2) | (f2h(o3) << 16);
        if (node16 < N)
            *(uint2*)(hout + (size_t)node16 * 64 + mt * 16 + q * 4) = pk;
    }
}

// Phase 1: dense partials, no atomics. gpart[(graph*SPLIT+sp)*192 + t].
__global__ __launch_bounds__(192) void readout_part_kernel(
        const ushort_t* __restrict__ H, const int* __restrict__ gids,
        float* __restrict__ gpart, int N) {
    int graph = blockIdx.x / SPLIT;
    int sp    = blockIdx.x % SPLIT;
    int lo = 0, hi = N;
    while (lo < hi) { int mid = (lo + hi) >> 1; if (gids[mid] < graph) lo = mid + 1; else hi = mid; }
    int start = lo;
    int lo2 = start, hi2 = N;
    while (lo2 < hi2) { int mid = (lo2 + hi2) >> 1; if (gids[mid] < graph + 1) lo2 = mid + 1; else hi2 = mid; }
    int end = lo2;
    int t = threadIdx.x;            // 0..191
    int l = t >> 6, d = t & 63;
    float acc = 0.0f;
    int cnt = end - start;
    if (cnt > 0) {
        int per = (cnt + SPLIT - 1) / SPLIT;
        int cs = start + sp * per;
        int ce = min(cs + per, end);
        const ushort_t* Hl = H + (size_t)l * N * 64;
        for (int n = cs; n < ce; ++n)
            acc += (float)__builtin_bit_cast(_Float16, Hl[(size_t)n * 64 + d]);
    }
    gpart[(size_t)(graph * SPLIT + sp) * 192 + t] = acc;   // unconditional
}

// Phase 2 fused with MLP: sum 16 partials -> gr, then 2-layer MLP.
__global__ __launch_bounds__(192) void mlp_kernel(
        const float* __restrict__ gpart,
        const float* __restrict__ W1, const float* __restrict__ b1,
        const float* __restrict__ W2, const float* __restrict__ b2,
        float* __restrict__ out) {
    __shared__ float gr[192];
    __shared__ float hid[128];
    int graph = blockIdx.x;
    int t = threadIdx.x;
    float a = 0.f;
    #pragma unroll
    for (int sp = 0; sp < SPLIT; ++sp)
        a += gpart[(size_t)(graph * SPLIT + sp) * 192 + t];
    gr[t] = a;
    __syncthreads();
    if (t < 128) {
        float s = b1[t];
        for (int k = 0; k < 192; ++k) s = fmaf(gr[k], W1[k * 128 + t], s);
        hid[t] = fmaxf(s, 0.0f);
    }
    __syncthreads();
    if (t < 32) {
        float s = b2[t];
        for (int k = 0; k < 128; ++k) s = fmaf(hid[k], W2[k * 32 + t], s);
        out[graph * 32 + t] = s;
    }
}

extern "C" void kernel_launch(void* const* d_in, const int* in_sizes, int n_in,
                              void* d_out, int out_size, void* d_ws, size_t ws_size,
                              hipStream_t stream) {
    const float* x     = (const float*)d_in[0];
    const float* gin_W = (const float*)d_in[1];
    const float* gin_b = (const float*)d_in[2];
    const float* eps   = (const float*)d_in[3];
    const float* r_W1  = (const float*)d_in[4];
    const float* r_b1  = (const float*)d_in[5];
    const float* r_W2  = (const float*)d_in[6];
    const float* r_b2  = (const float*)d_in[7];
    const int*   src   = (const int*)d_in[8];
    const int*   dst   = (const int*)d_in[9];
    const int*   gids  = (const int*)d_in[10];

    int N = in_sizes[0] / 64;       // 100000
    int E = in_sizes[8];            // 1200000
    int B = out_size / 32;          // 256

    int nbkt = (N + BS - 1) / BS;   // 196 (<= 256)
    int ebpb = (E + NBLK - 1) / NBLK;
    int n4 = N * 64 / 4;
    int castBlocks = (n4 + 255) / 256;
    int wtotal = 3 * 4096;
    int prepBlocks = (wtotal + 255) / 256;

    // workspace layout (4B words), all regions fully written before read:
    //   gpart[B*SPLIT*192]
    //   cnt2d[NBLK*nbkt] | blkoff[nbkt*NBLK] | btot[nbkt] | bbase[nbkt+1]
    //   offsets[N+1] | bkt[E] | csr[E] | pad
    //   xh[N*64 f16] | H[3*N*64 f16] | whi[3*4096] | wlo[3*4096]
    int* ws       = (int*)d_ws;
    float* gpart  = (float*)ws;
    int* cnt2d    = ws + (size_t)B * SPLIT * 192;
    int* blkoff   = cnt2d + (size_t)NBLK * nbkt;
    int* btot     = blkoff + (size_t)nbkt * NBLK;
    int* bbase    = btot + nbkt;
    int* offsets  = bbase + (nbkt + 1);
    unsigned int* bkt = (unsigned int*)(offsets + (N + 1));
    int* csr      = (int*)(bkt + E);
    size_t w      = (size_t)(csr + E - ws);
    w = (w + 15) & ~(size_t)15;     // 64B align
    ushort_t* xh  = (ushort_t*)(ws + w);
    ushort_t* H   = xh + (size_t)N * 64;
    ushort_t* whi = H + 3 * (size_t)N * 64;
    ushort_t* wlo = whi + 3 * 4096;

    pre_kernel<<<NBLK + castBlocks + prepBlocks, 256, 0, stream>>>(
        dst, cnt2d, E, nbkt, ebpb, x, xh, n4, castBlocks, gin_W, whi, wlo, wtotal);
    colscan_kernel<<<nbkt, 256, 0, stream>>>(cnt2d, blkoff, btot, nbkt);
    bucket_base_kernel<<<1, 256, 0, stream>>>(btot, bbase, offsets, nbkt, N, E);
    bucket_scatter_kernel<<<NBLK, 256, 0, stream>>>(src, dst, bbase, blkoff, bkt, E, nbkt, ebpb);
    csr_build_kernel<<<nbkt, 256, 0, stream>>>(bkt, bbase, offsets, csr, N, nbkt);

    int lbk = (N + 63) / 64;        // 4 tiles (waves) of 16 nodes per block
    ushort_t* H0 = H;
    ushort_t* H1 = H + (size_t)N * 64;
    ushort_t* H2 = H + 2 * (size_t)N * 64;

    layer_kernel<<<lbk, 256, 0, stream>>>(xh, H0, offsets, csr, whi, wlo, gin_b, eps, 0, N, E);
    layer_kernel<<<lbk, 256, 0, stream>>>(H0, H1, offsets, csr, whi, wlo, gin_b, eps, 1, N, E);
    layer_kernel<<<lbk, 256, 0, stream>>>(H1, H2, offsets, csr, whi, wlo, gin_b, eps, 2, N, E);

    readout_part_kernel<<<B * SPLIT, 192, 0, stream>>>(H, gids, gpart, N);
    mlp_kernel<<<B, 192, 0, stream>>>(gpart, r_W1, r_b1, r_W2, r_b2, (float*)d_out);
}